// Round 8
// baseline (521.367 us; speedup 1.0000x reference)
//
#include <hip/hip_runtime.h>

#define Hd 128
#define LDA 136   // LDS leading dim (bf16 elems); LDA/2 = 68 uints per row

typedef __attribute__((ext_vector_type(8))) short short8;   // 8 bf16 = 4 VGPRs
typedef __attribute__((ext_vector_type(4))) float f32x4;

__device__ __forceinline__ unsigned short f2bf(float f) {
    union { float f; unsigned u; } v; v.f = f;
    unsigned r = v.u + 0x7FFFu + ((v.u >> 16) & 1u);   // RNE
    return (unsigned short)(r >> 16);
}

// ---------- graph prep ----------
__global__ __launch_bounds__(256) void zero_kernel(int* __restrict__ p, int n) {
    int i = blockIdx.x * 256 + threadIdx.x;
    if (i < n) p[i] = 0;
}

// histogram over (rel*N + dst) buckets  — rel-major so per-(relation,row-block)
// edge ranges are contiguous for the fused GEMM staging
__global__ __launch_bounds__(256) void count_kernel(const int* __restrict__ dst,
                                                    const int* __restrict__ et,
                                                    int* __restrict__ cnt2, int E, int N) {
    int e = blockIdx.x * 256 + threadIdx.x;
    if (e < E) atomicAdd(&cnt2[et[e] * N + dst[e]], 1);
}

// per-256-chunk sums
__global__ __launch_bounds__(256) void reduce_kernel(const int* __restrict__ cnt2,
                                                     int* __restrict__ bsum, int n) {
    __shared__ int ws[4];
    const int tid = threadIdx.x;
    int i = blockIdx.x * 256 + tid;
    int v = (i < n) ? cnt2[i] : 0;
#pragma unroll
    for (int off = 32; off > 0; off >>= 1) v += __shfl_down(v, off);
    if ((tid & 63) == 0) ws[tid >> 6] = v;
    __syncthreads();
    if (tid == 0) bsum[blockIdx.x] = ws[0] + ws[1] + ws[2] + ws[3];
}

// exclusive scan of cnt2 -> cur; each block computes its own bsum prefix (bsum is raw sums)
__global__ __launch_bounds__(256) void apply_kernel(const int* __restrict__ cnt2,
                                                    const int* __restrict__ bsum,
                                                    int* __restrict__ cur, int n) {
    __shared__ int wsum[4];
    __shared__ int bpre_s;
    const int tid = threadIdx.x;
    const int lane = tid & 63, wid = tid >> 6;
    // block prefix = sum bsum[0..blockIdx.x)
    int p = 0;
    for (int k = tid; k < blockIdx.x; k += 256) p += bsum[k];
#pragma unroll
    for (int off = 32; off > 0; off >>= 1) p += __shfl_down(p, off);
    if (lane == 0) wsum[wid] = p;
    __syncthreads();
    if (tid == 0) bpre_s = wsum[0] + wsum[1] + wsum[2] + wsum[3];
    __syncthreads();
    // in-block scan
    int i = blockIdx.x * 256 + tid;
    int x = (i < n) ? cnt2[i] : 0;
    int incl = x;
#pragma unroll
    for (int off = 1; off < 64; off <<= 1) {
        int t = __shfl_up(incl, off);
        if (lane >= off) incl += t;
    }
    __syncthreads();
    if (lane == 63) wsum[wid] = incl;
    __syncthreads();
    int wpre = 0;
    for (int k = 0; k < wid; ++k) wpre += wsum[k];
    if (i < n) cur[i] = incl - x + wpre + bpre_s;
}

// counting-sort placement: epk sorted by (rel,dst), payload = src.
// post-condition: cur[b] == end offset of bucket b (start(b) = cur[b-1], cur[-1]=0)
__global__ __launch_bounds__(256) void place_kernel(const int* __restrict__ src,
                                                    const int* __restrict__ dst,
                                                    const int* __restrict__ et,
                                                    int* __restrict__ cur,
                                                    unsigned int* __restrict__ epk,
                                                    int E, int N) {
    int e = blockIdx.x * 256 + threadIdx.x;
    if (e < E) {
        int pos = atomicAdd(&cur[et[e] * N + dst[e]], 1);
        epk[pos] = (unsigned int)src[e];
    }
}

// ---------- dtype prep ----------
__global__ __launch_bounds__(256) void cvt_bf16_kernel(const float* __restrict__ in,
                                                       unsigned short* __restrict__ out,
                                                       int n4) {
    int i = blockIdx.x * 256 + threadIdx.x;
    if (i >= n4) return;
    float4 v = ((const float4*)in)[i];
    ushort4 o;
    o.x = f2bf(v.x); o.y = f2bf(v.y); o.z = f2bf(v.z); o.w = f2bf(v.w);
    ((ushort4*)out)[i] = o;
}

// All 18 weight matrices in one launch. Block b: slot b of Bt (n-major transposed bf16).
__global__ __launch_bounds__(256) void prep_w_all(const float* __restrict__ root1,
                                                  const float* __restrict__ W1,
                                                  const float* __restrict__ root2,
                                                  const float* __restrict__ W2,
                                                  unsigned short* __restrict__ Bt) {
    __shared__ float S[128 * 129];
    const int b = blockIdx.x;
    const float* Ws;
    if (b == 0)       Ws = root1;
    else if (b < 9)   Ws = W1 + (size_t)(b - 1) * 16384;
    else if (b == 9)  Ws = root2;
    else              Ws = W2 + (size_t)(b - 10) * 16384;
    unsigned short* Bd = Bt + (size_t)b * 16384;
    const int tid = threadIdx.x;
#pragma unroll 8
    for (int i = 0; i < 64; ++i) {
        int idx = i * 256 + tid;
        S[(idx >> 7) * 129 + (idx & 127)] = Ws[idx];
    }
    __syncthreads();
#pragma unroll 8
    for (int i = 0; i < 64; ++i) {
        int idx = i * 256 + tid;
        int n = idx >> 7, k = idx & 127;
        Bd[idx] = f2bf(S[k * 129 + n]);
    }
}

// ---------- fused layer: acc = A0@Bt[0] + sum_r mean_agg(A0)@Bt[1+r] ----------
// Aggregation is done in the A-tile staging: stage r builds agg[r] rows for this
// block's 128 nodes directly in LDS from (rel,dst)-sorted CSR. No agg buffer.
// mode 1: outb = bf16(relu(acc + bias))        mode 2: outf = relu(acc+bias).Wc + bc
__global__ __launch_bounds__(256, 2) void gemm_fused(const unsigned short* __restrict__ A0,
                                                     const int* __restrict__ cur,
                                                     const unsigned int* __restrict__ epk,
                                                     const unsigned short* __restrict__ Bt9,
                                                     const float* __restrict__ bias,
                                                     const float* __restrict__ Wc,
                                                     const float* __restrict__ bc,
                                                     unsigned short* __restrict__ outb,
                                                     float* __restrict__ outf,
                                                     int M, int N, int mode) {
    __shared__ __align__(16) unsigned short As[128 * LDA];
    __shared__ __align__(16) unsigned short Bs[128 * LDA];
    const int tid = threadIdx.x;
    const int rowBase = blockIdx.x * 128;
    const int wave = tid >> 6, lane = tid & 63;
    const int lm = lane & 15, lk = (lane >> 4) * 8;
    const unsigned int* x32 = (const unsigned int*)A0;   // 2 bf16 per uint
    unsigned int* As32 = (unsigned int*)As;

    f32x4 acc[2][8];
#pragma unroll
    for (int mt = 0; mt < 2; ++mt)
#pragma unroll
        for (int nt = 0; nt < 8; ++nt) acc[mt][nt] = (f32x4){0.f, 0.f, 0.f, 0.f};

    // ---- stage 0: root — A0 + Bt[0], coalesced ----
#pragma unroll
    for (int i = 0; i < 8; ++i) {
        int idx = i * 256 + tid;
        int r = idx >> 4, c16 = idx & 15;
        int grow = rowBase + r; if (grow >= M) grow = M - 1;
        *(float4*)&As[r * LDA + c16 * 8] = *(const float4*)&A0[(size_t)grow * Hd + c16 * 8];
        *(float4*)&Bs[r * LDA + c16 * 8] = *(const float4*)&Bt9[idx * 8];
    }
    __syncthreads();
#pragma unroll
    for (int ks = 0; ks < 4; ++ks) {
        const int k0 = ks * 32 + lk;
        short8 af0 = *(const short8*)&As[(wave * 32 + lm) * LDA + k0];
        short8 af1 = *(const short8*)&As[(wave * 32 + 16 + lm) * LDA + k0];
#pragma unroll
        for (int nt = 0; nt < 8; ++nt) {
            short8 bf = *(const short8*)&Bs[(nt * 16 + lm) * LDA + k0];
            acc[0][nt] = __builtin_amdgcn_mfma_f32_16x16x32_bf16(af0, bf, acc[0][nt], 0, 0, 0);
            acc[1][nt] = __builtin_amdgcn_mfma_f32_16x16x32_bf16(af1, bf, acc[1][nt], 0, 0, 0);
        }
    }

    // ---- stages 1..8: relation r — gather-aggregate A-tile in LDS + Bt[1+r] ----
    for (int rel = 0; rel < 8; ++rel) {
        __syncthreads();   // previous stage's LDS reads complete
        const unsigned short* Btt = Bt9 + (size_t)(1 + rel) * 16384;
#pragma unroll
        for (int i = 0; i < 8; ++i) {
            int idx = i * 256 + tid;
            *(float4*)&Bs[(idx >> 4) * LDA + (idx & 15) * 8] = *(const float4*)&Btt[idx * 8];
        }
        // bucket bounds for this wave's 32 rows (lane<32): bucket b = rel*N + node
        int node = rowBase + wave * 32 + lane;
        int e_end = 0;
        if (lane < 32) e_end = cur[rel * N + min(node, N - 1)];
        int begv = __shfl_up(e_end, 1);
        if (lane == 0) {
            int bidx = rel * N + min(node, N - 1);
            begv = (bidx == 0) ? 0 : cur[bidx - 1];
        }
        const int begW = __builtin_amdgcn_readfirstlane(begv);
        const int endW = __builtin_amdgcn_readfirstlane(__shfl(e_end, 31));
        int ep_v = 0;   // lane-parallel prefetch of the wave's edge span (covers <=64)
        if (begW + lane < endW) ep_v = (int)epk[begW + lane];

        for (int i = 0; i < 32; ++i) {
            const int beg = __builtin_amdgcn_readfirstlane(__shfl(begv, i));
            const int end = __builtin_amdgcn_readfirstlane(__shfl(e_end, i));
            float a0 = 0.f, a1 = 0.f;
            for (int e = beg; e < end; ++e) {
                int io = e - begW;
                unsigned int s = (io < 64)
                    ? (unsigned int)__builtin_amdgcn_readfirstlane(__shfl(ep_v, io))
                    : epk[e];
                unsigned int v = x32[(size_t)s * 64 + lane];
                a0 += __uint_as_float(v << 16);
                a1 += __uint_as_float(v & 0xffff0000u);
            }
            float w = 1.0f / (float)max(end - beg, 1);
            unsigned int lo = f2bf(a0 * w);
            unsigned int hi = f2bf(a1 * w);
            As32[(wave * 32 + i) * (LDA / 2) + lane] = lo | (hi << 16);
        }
        __syncthreads();
#pragma unroll
        for (int ks = 0; ks < 4; ++ks) {
            const int k0 = ks * 32 + lk;
            short8 af0 = *(const short8*)&As[(wave * 32 + lm) * LDA + k0];
            short8 af1 = *(const short8*)&As[(wave * 32 + 16 + lm) * LDA + k0];
#pragma unroll
            for (int nt = 0; nt < 8; ++nt) {
                short8 bf = *(const short8*)&Bs[(nt * 16 + lm) * LDA + k0];
                acc[0][nt] = __builtin_amdgcn_mfma_f32_16x16x32_bf16(af0, bf, acc[0][nt], 0, 0, 0);
                acc[1][nt] = __builtin_amdgcn_mfma_f32_16x16x32_bf16(af1, bf, acc[1][nt], 0, 0, 0);
            }
        }
    }

    // epilogue. C/D layout: col = nt*16 + lm, row = wave*32 + mt*16 + (lane>>4)*4 + reg
    const int rquad = (lane >> 4) * 4;
    float biasr[8], wc[8];
#pragma unroll
    for (int nt = 0; nt < 8; ++nt) biasr[nt] = bias[nt * 16 + lm];
    if (mode == 2) {
#pragma unroll
        for (int nt = 0; nt < 8; ++nt) wc[nt] = Wc[nt * 16 + lm];
    }
    const float bc0 = (mode == 2) ? bc[0] : 0.f;

#pragma unroll
    for (int mt = 0; mt < 2; ++mt)
#pragma unroll
        for (int reg = 0; reg < 4; ++reg) {
            int row = rowBase + wave * 32 + mt * 16 + rquad + reg;
            if (mode == 1) {
                if (row >= M) continue;
#pragma unroll
                for (int nt = 0; nt < 8; ++nt) {
                    float v = fmaxf(acc[mt][nt][reg] + biasr[nt], 0.f);
                    outb[(size_t)row * Hd + nt * 16 + lm] = f2bf(v);
                }
            } else {
                float s = 0.f;
#pragma unroll
                for (int nt = 0; nt < 8; ++nt)
                    s += fmaxf(acc[mt][nt][reg] + biasr[nt], 0.f) * wc[nt];
                s += __shfl_xor(s, 1);
                s += __shfl_xor(s, 2);
                s += __shfl_xor(s, 4);
                s += __shfl_xor(s, 8);
                if (lm == 0 && row < M) outf[row] = s + bc0;
            }
        }
}

extern "C" void kernel_launch(void* const* d_in, const int* in_sizes, int n_in,
                              void* d_out, int out_size, void* d_ws, size_t ws_size,
                              hipStream_t stream) {
    const float* x     = (const float*)d_in[0];
    const int*   ei    = (const int*)d_in[1];
    const int*   et    = (const int*)d_in[2];
    const float* W1    = (const float*)d_in[3];
    const float* root1 = (const float*)d_in[4];
    const float* b1    = (const float*)d_in[5];
    const float* W2    = (const float*)d_in[6];
    const float* root2 = (const float*)d_in[7];
    const float* b2    = (const float*)d_in[8];
    const float* Wc    = (const float*)d_in[9];
    const float* bc    = (const float*)d_in[10];
    float* out = (float*)d_out;

    const int N = in_sizes[0] / Hd;
    const int E = in_sizes[2];
    const int R = in_sizes[3] / (Hd * Hd);   // == 8
    const int* src  = ei;
    const int* dstp = ei + E;

    const size_t NH = (size_t)N * Hd;
    const int n2 = R * N;                    // (rel,dst) bucket count
    const int nBlocks2 = (n2 + 255) / 256;

    size_t off = 0;
    auto carve = [&](size_t bytes) -> char* {
        char* p = (char*)d_ws + off;
        off += (bytes + 255) & ~(size_t)255;
        return p;
    };
    unsigned short* xbf  = (unsigned short*)carve(NH * 2);
    unsigned short* hbf  = (unsigned short*)carve(NH * 2);
    unsigned short* Bt   = (unsigned short*)carve((size_t)2 * 9 * 16384 * 2);
    int*            cnt2 = (int*)carve((size_t)n2 * 4);
    int*            cur  = (int*)carve((size_t)n2 * 4);
    int*            bsum = (int*)carve((size_t)nBlocks2 * 4);
    unsigned int*   epk  = (unsigned int*)carve((size_t)E * 4);
    if (off > ws_size) return;

    // graph prep: histogram -> CSR over (rel*N + dst)
    zero_kernel<<<nBlocks2, 256, 0, stream>>>(cnt2, n2);
    count_kernel<<<(E + 255) / 256, 256, 0, stream>>>(dstp, et, cnt2, E, N);
    reduce_kernel<<<nBlocks2, 256, 0, stream>>>(cnt2, bsum, n2);
    apply_kernel<<<nBlocks2, 256, 0, stream>>>(cnt2, bsum, cur, n2);
    place_kernel<<<(E + 255) / 256, 256, 0, stream>>>(src, dstp, et, cur, epk, E, N);

    // dtype prep
    const int n4 = (int)(NH / 4);
    cvt_bf16_kernel<<<(n4 + 255) / 256, 256, 0, stream>>>(x, xbf, n4);
    prep_w_all<<<18, 256, 0, stream>>>(root1, W1, root2, W2, Bt);

    const int Mtiles = (N + 127) / 128;

    // layer 1: fused aggregate+GEMM -> hbf (relu, bf16)
    gemm_fused<<<Mtiles, 256, 0, stream>>>(xbf, cur, epk, Bt, b1, nullptr, nullptr,
                                           hbf, nullptr, N, N, 1);
    // layer 2: fused aggregate+GEMM + classifier -> out
    gemm_fused<<<Mtiles, 256, 0, stream>>>(hbf, cur, epk, Bt + (size_t)9 * 16384, b2, Wc, bc,
                                           nullptr, out, N, N, 2);
}

// Round 9
// 305.701 us; speedup vs baseline: 1.7055x; 1.7055x over previous
//
#include <hip/hip_runtime.h>

#define Hd 128
#define LDA 136   // LDS leading dim (bf16 elems)

typedef __attribute__((ext_vector_type(8))) short short8;   // 8 bf16 = 4 VGPRs
typedef __attribute__((ext_vector_type(4))) float f32x4;

__device__ __forceinline__ unsigned short f2bf(float f) {
    union { float f; unsigned u; } v; v.f = f;
    unsigned r = v.u + 0x7FFFu + ((v.u >> 16) & 1u);   // RNE
    return (unsigned short)(r >> 16);
}

// ---------- graph prep ----------
__global__ __launch_bounds__(256) void zero_kernel(int* __restrict__ p, int n) {
    int i = blockIdx.x * 256 + threadIdx.x;
    if (i < n) p[i] = 0;
}

// histogram over (dst*8 + rel) buckets
__global__ __launch_bounds__(256) void count_kernel(const int* __restrict__ dst,
                                                    const int* __restrict__ et,
                                                    int* __restrict__ cnt2, int E) {
    int e = blockIdx.x * 256 + threadIdx.x;
    if (e < E) atomicAdd(&cnt2[dst[e] * 8 + et[e]], 1);
}

// per-256-chunk sums
__global__ __launch_bounds__(256) void reduce_kernel(const int* __restrict__ cnt2,
                                                     int* __restrict__ bsum, int n) {
    __shared__ int ws[4];
    const int tid = threadIdx.x;
    int i = blockIdx.x * 256 + tid;
    int v = (i < n) ? cnt2[i] : 0;
#pragma unroll
    for (int off = 32; off > 0; off >>= 1) v += __shfl_down(v, off);
    if ((tid & 63) == 0) ws[tid >> 6] = v;
    __syncthreads();
    if (tid == 0) bsum[blockIdx.x] = ws[0] + ws[1] + ws[2] + ws[3];
}

// exclusive scan of cnt2 -> cur (each block sums its own bsum prefix); also inv2
__global__ __launch_bounds__(256) void apply_kernel(const int* __restrict__ cnt2,
                                                    const int* __restrict__ bsum,
                                                    int* __restrict__ cur,
                                                    float* __restrict__ inv2, int n) {
    __shared__ int wsum[4];
    __shared__ int bpre_s;
    const int tid = threadIdx.x;
    const int lane = tid & 63, wid = tid >> 6;
    int p = 0;
    for (int k = tid; k < blockIdx.x; k += 256) p += bsum[k];
#pragma unroll
    for (int off = 32; off > 0; off >>= 1) p += __shfl_down(p, off);
    if (lane == 0) wsum[wid] = p;
    __syncthreads();
    if (tid == 0) bpre_s = wsum[0] + wsum[1] + wsum[2] + wsum[3];
    __syncthreads();
    int i = blockIdx.x * 256 + tid;
    int x = (i < n) ? cnt2[i] : 0;
    int incl = x;
#pragma unroll
    for (int off = 1; off < 64; off <<= 1) {
        int t = __shfl_up(incl, off);
        if (lane >= off) incl += t;
    }
    __syncthreads();
    if (lane == 63) wsum[wid] = incl;
    __syncthreads();
    int wpre = 0;
    for (int k = 0; k < wid; ++k) wpre += wsum[k];
    if (i < n) {
        cur[i] = incl - x + wpre + bpre_s;
        inv2[i] = 1.0f / (float)max(x, 1);
    }
}

// counting-sort placement: epk sorted by (dst,rel), payload = src.
// post-condition: cur[b] == end offset of bucket b (start(b) = cur[b-1], cur[-1]=0)
__global__ __launch_bounds__(256) void place_kernel(const int* __restrict__ src,
                                                    const int* __restrict__ dst,
                                                    const int* __restrict__ et,
                                                    int* __restrict__ cur,
                                                    unsigned int* __restrict__ epk, int E) {
    int e = blockIdx.x * 256 + threadIdx.x;
    if (e < E) {
        int pos = atomicAdd(&cur[dst[e] * 8 + et[e]], 1);
        epk[pos] = (unsigned int)src[e];
    }
}

// ---------- dtype prep ----------
__global__ __launch_bounds__(256) void cvt_bf16_kernel(const float* __restrict__ in,
                                                       unsigned short* __restrict__ out,
                                                       int n4) {
    int i = blockIdx.x * 256 + threadIdx.x;
    if (i >= n4) return;
    float4 v = ((const float4*)in)[i];
    ushort4 o;
    o.x = f2bf(v.x); o.y = f2bf(v.y); o.z = f2bf(v.z); o.w = f2bf(v.w);
    ((ushort4*)out)[i] = o;
}

// All 18 weight matrices in one launch. Block b: slot b of Bt (n-major transposed bf16).
__global__ __launch_bounds__(256) void prep_w_all(const float* __restrict__ root1,
                                                  const float* __restrict__ W1,
                                                  const float* __restrict__ root2,
                                                  const float* __restrict__ W2,
                                                  unsigned short* __restrict__ Bt) {
    __shared__ float S[128 * 129];
    const int b = blockIdx.x;
    const float* Ws;
    if (b == 0)       Ws = root1;
    else if (b < 9)   Ws = W1 + (size_t)(b - 1) * 16384;
    else if (b == 9)  Ws = root2;
    else              Ws = W2 + (size_t)(b - 10) * 16384;
    unsigned short* Bd = Bt + (size_t)b * 16384;
    const int tid = threadIdx.x;
#pragma unroll 8
    for (int i = 0; i < 64; ++i) {
        int idx = i * 256 + tid;
        S[(idx >> 7) * 129 + (idx & 127)] = Ws[idx];
    }
    __syncthreads();
#pragma unroll 8
    for (int i = 0; i < 64; ++i) {
        int idx = i * 256 + tid;
        int n = idx >> 7, k = idx & 127;
        Bd[idx] = f2bf(S[k * 129 + n]);
    }
}

// ---------- input-space aggregation over (dst,rel)-sorted CSR ----------
// one wave per dst node. Half-wave edge pairing: lanes 0-31 edge e, lanes 32-63
// edge e+1; each lane loads uint2 (4 bf16 channels). Per-relation cross-half
// combine via shfl_xor(32). Edge srcs prefetched lane-parallel once per node.
__global__ __launch_bounds__(256) void gather_agg(const unsigned short* __restrict__ xsrc,
                                                  const int* __restrict__ cur,
                                                  const unsigned int* __restrict__ epk,
                                                  const float* __restrict__ inv2,
                                                  unsigned short* __restrict__ agg, int N) {
    const int lane = threadIdx.x & 63;
    const int half = lane >> 5;          // 0: edge e, 1: edge e+1
    const int lh = lane & 31;            // channel group: 4 ch per lane
    const int node = (int)((blockIdx.x * 256 + threadIdx.x) >> 6);
    if (node >= N) return;
    int b9 = 0;
    if (lane < 9) {
        int idx = node * 8 + lane - 1;
        b9 = (idx < 0) ? 0 : cur[idx];
    }
    float winv = (lane < 8) ? inv2[node * 8 + lane] : 0.f;
    const int beg0 = __builtin_amdgcn_readfirstlane(__shfl(b9, 0));
    const int end7 = __builtin_amdgcn_readfirstlane(__shfl(b9, 8));

    // lane-parallel prefetch of up to 64 edge srcs (covers virtually all nodes)
    int ep_v = 0;
    if (beg0 + lane < end7) ep_v = (int)epk[beg0 + lane];

    const uint2* x64 = (const uint2*)xsrc;      // row = 32 uint2 (128 bf16)
    uint2* agg64 = (uint2*)agg;
    const size_t NR4 = (size_t)N * 32;          // uint2 per relation matrix

#pragma unroll
    for (int r = 0; r < 8; ++r) {
        const int beg = __builtin_amdgcn_readfirstlane(__shfl(b9, r));
        const int end = __builtin_amdgcn_readfirstlane(__shfl(b9, r + 1));
        float a0 = 0.f, a1 = 0.f, a2 = 0.f, a3 = 0.f;
        for (int e = beg; e < end; e += 2) {
            int idx = e + half;
            if (idx < end) {
                int io = idx - beg0;
                unsigned int s = (io < 64) ? (unsigned int)__shfl(ep_v, io)
                                           : epk[idx];
                uint2 v = x64[(size_t)s * 32 + lh];
                a0 += __uint_as_float(v.x << 16);
                a1 += __uint_as_float(v.x & 0xffff0000u);
                a2 += __uint_as_float(v.y << 16);
                a3 += __uint_as_float(v.y & 0xffff0000u);
            }
        }
        a0 += __shfl_xor(a0, 32);
        a1 += __shfl_xor(a1, 32);
        a2 += __shfl_xor(a2, 32);
        a3 += __shfl_xor(a3, 32);
        float w = __shfl(winv, r);
        if (half == 0) {
            uint2 o;
            o.x = (unsigned int)f2bf(a0 * w) | ((unsigned int)f2bf(a1 * w) << 16);
            o.y = (unsigned int)f2bf(a2 * w) | ((unsigned int)f2bf(a3 * w) << 16);
            agg64[(size_t)r * NR4 + (size_t)node * 32 + lh] = o;
        }
    }
}

// ---------- fused layer GEMM: acc = A0@Bt[0] + sum_r agg[r]@Bt[1+r]  (K_eff = 1152) ----------
// R5/R7 structure: two-barrier VGPR staging per stage (no register prefetch — spills; see R6).
// mode 1: outb = bf16(relu(acc + bias))        mode 2: outf = relu(acc+bias).Wc + bc
__global__ __launch_bounds__(256, 2) void gemm_fused(const unsigned short* __restrict__ A0,
                                                     const unsigned short* __restrict__ agg,
                                                     const unsigned short* __restrict__ Bt9,
                                                     const float* __restrict__ bias,
                                                     const float* __restrict__ Wc,
                                                     const float* __restrict__ bc,
                                                     unsigned short* __restrict__ outb,
                                                     float* __restrict__ outf,
                                                     int M, int mode) {
    __shared__ __align__(16) unsigned short As[128 * LDA];
    __shared__ __align__(16) unsigned short Bs[128 * LDA];
    const int tid = threadIdx.x;
    const int rowBase = blockIdx.x * 128;
    const int wave = tid >> 6, lane = tid & 63;
    const int lm = lane & 15, lk = (lane >> 4) * 8;
    const size_t NH = (size_t)M * Hd;

    f32x4 acc[2][8];
#pragma unroll
    for (int mt = 0; mt < 2; ++mt)
#pragma unroll
        for (int nt = 0; nt < 8; ++nt) acc[mt][nt] = (f32x4){0.f, 0.f, 0.f, 0.f};

    for (int t = 0; t < 9; ++t) {
        const unsigned short* At = (t == 0) ? A0 : agg + (size_t)(t - 1) * NH;
        const unsigned short* Btt = Bt9 + (size_t)t * 16384;
        __syncthreads();   // previous stage's LDS reads complete
#pragma unroll
        for (int i = 0; i < 8; ++i) {
            int idx = i * 256 + tid;
            int r = idx >> 4, c16 = idx & 15;
            int grow = rowBase + r; if (grow >= M) grow = M - 1;
            *(float4*)&As[r * LDA + c16 * 8] = *(const float4*)&At[(size_t)grow * Hd + c16 * 8];
            *(float4*)&Bs[r * LDA + c16 * 8] = *(const float4*)&Btt[idx * 8];
        }
        __syncthreads();
#pragma unroll
        for (int ks = 0; ks < 4; ++ks) {
            const int k0 = ks * 32 + lk;
            short8 af0 = *(const short8*)&As[(wave * 32 + lm) * LDA + k0];
            short8 af1 = *(const short8*)&As[(wave * 32 + 16 + lm) * LDA + k0];
#pragma unroll
            for (int nt = 0; nt < 8; ++nt) {
                short8 bf = *(const short8*)&Bs[(nt * 16 + lm) * LDA + k0];
                acc[0][nt] = __builtin_amdgcn_mfma_f32_16x16x32_bf16(af0, bf, acc[0][nt], 0, 0, 0);
                acc[1][nt] = __builtin_amdgcn_mfma_f32_16x16x32_bf16(af1, bf, acc[1][nt], 0, 0, 0);
            }
        }
    }

    // epilogue. C/D layout: col = nt*16 + lm, row = wave*32 + mt*16 + (lane>>4)*4 + reg
    const int rquad = (lane >> 4) * 4;
    float biasr[8], wc[8];
#pragma unroll
    for (int nt = 0; nt < 8; ++nt) biasr[nt] = bias[nt * 16 + lm];
    if (mode == 2) {
#pragma unroll
        for (int nt = 0; nt < 8; ++nt) wc[nt] = Wc[nt * 16 + lm];
    }
    const float bc0 = (mode == 2) ? bc[0] : 0.f;

#pragma unroll
    for (int mt = 0; mt < 2; ++mt)
#pragma unroll
        for (int reg = 0; reg < 4; ++reg) {
            int row = rowBase + wave * 32 + mt * 16 + rquad + reg;
            if (mode == 1) {
                if (row >= M) continue;
#pragma unroll
                for (int nt = 0; nt < 8; ++nt) {
                    float v = fmaxf(acc[mt][nt][reg] + biasr[nt], 0.f);
                    outb[(size_t)row * Hd + nt * 16 + lm] = f2bf(v);
                }
            } else {
                float s = 0.f;
#pragma unroll
                for (int nt = 0; nt < 8; ++nt)
                    s += fmaxf(acc[mt][nt][reg] + biasr[nt], 0.f) * wc[nt];
                s += __shfl_xor(s, 1);
                s += __shfl_xor(s, 2);
                s += __shfl_xor(s, 4);
                s += __shfl_xor(s, 8);
                if (lm == 0 && row < M) outf[row] = s + bc0;
            }
        }
}

extern "C" void kernel_launch(void* const* d_in, const int* in_sizes, int n_in,
                              void* d_out, int out_size, void* d_ws, size_t ws_size,
                              hipStream_t stream) {
    const float* x     = (const float*)d_in[0];
    const int*   ei    = (const int*)d_in[1];
    const int*   et    = (const int*)d_in[2];
    const float* W1    = (const float*)d_in[3];
    const float* root1 = (const float*)d_in[4];
    const float* b1    = (const float*)d_in[5];
    const float* W2    = (const float*)d_in[6];
    const float* root2 = (const float*)d_in[7];
    const float* b2    = (const float*)d_in[8];
    const float* Wc    = (const float*)d_in[9];
    const float* bc    = (const float*)d_in[10];
    float* out = (float*)d_out;

    const int N = in_sizes[0] / Hd;
    const int E = in_sizes[2];
    const int R = in_sizes[3] / (Hd * Hd);   // == 8
    const int* src  = ei;
    const int* dstp = ei + E;

    const size_t NH = (size_t)N * Hd;
    const int n2 = N * 8;                    // (dst,rel) bucket count
    const int nBlocks2 = (n2 + 255) / 256;

    size_t off = 0;
    auto carve = [&](size_t bytes) -> char* {
        char* p = (char*)d_ws + off;
        off += (bytes + 255) & ~(size_t)255;
        return p;
    };
    unsigned short* xbf  = (unsigned short*)carve(NH * 2);
    unsigned short* hbf  = (unsigned short*)carve(NH * 2);
    unsigned short* agg  = (unsigned short*)carve((size_t)R * NH * 2);
    unsigned short* Bt   = (unsigned short*)carve((size_t)2 * 9 * 16384 * 2);
    int*            cnt2 = (int*)carve((size_t)n2 * 4);
    float*          inv2 = (float*)carve((size_t)n2 * 4);
    int*            cur  = (int*)carve((size_t)n2 * 4);
    int*            bsum = (int*)carve((size_t)nBlocks2 * 4);
    unsigned int*   epk  = (unsigned int*)carve((size_t)E * 4);
    if (off > ws_size) return;

    // graph prep: histogram -> inv + CSR over (dst*8+rel)
    zero_kernel<<<nBlocks2, 256, 0, stream>>>(cnt2, n2);
    count_kernel<<<(E + 255) / 256, 256, 0, stream>>>(dstp, et, cnt2, E);
    reduce_kernel<<<nBlocks2, 256, 0, stream>>>(cnt2, bsum, n2);
    apply_kernel<<<nBlocks2, 256, 0, stream>>>(cnt2, bsum, cur, inv2, n2);
    place_kernel<<<(E + 255) / 256, 256, 0, stream>>>(src, dstp, et, cur, epk, E);

    // dtype prep
    const int n4 = (int)(NH / 4);
    cvt_bf16_kernel<<<(n4 + 255) / 256, 256, 0, stream>>>(x, xbf, n4);
    prep_w_all<<<18, 256, 0, stream>>>(root1, W1, root2, W2, Bt);

    const int Mtiles = (N + 127) / 128;
    const int nodeBlocks = (N + 3) / 4;

    // layer 1: aggregate x -> agg; fused GEMM -> hbf (relu, bf16)
    gather_agg<<<nodeBlocks, 256, 0, stream>>>(xbf, cur, epk, inv2, agg, N);
    gemm_fused<<<Mtiles, 256, 0, stream>>>(xbf, agg, Bt, b1, nullptr, nullptr,
                                           hbf, nullptr, N, 1);
    // layer 2: aggregate hbf -> agg; fused GEMM + classifier -> out
    gather_agg<<<nodeBlocks, 256, 0, stream>>>(hbf, cur, epk, inv2, agg, N);
    gemm_fused<<<Mtiles, 256, 0, stream>>>(hbf, agg, Bt + (size_t)9 * 16384, b2, Wc, bc,
                                           nullptr, out, N, 2);
}

// Round 10
// 283.149 us; speedup vs baseline: 1.8413x; 1.0796x over previous
//
#include <hip/hip_runtime.h>

#define Hd 128
#define LDA 136   // LDS leading dim (bf16 elems)

typedef __attribute__((ext_vector_type(8))) short short8;   // 8 bf16 = 4 VGPRs
typedef __attribute__((ext_vector_type(4))) float f32x4;

__device__ __forceinline__ unsigned short f2bf(float f) {
    union { float f; unsigned u; } v; v.f = f;
    unsigned r = v.u + 0x7FFFu + ((v.u >> 16) & 1u);   // RNE
    return (unsigned short)(r >> 16);
}

// ---------- graph prep ----------
// histogram over (dst*8 + rel) buckets
__global__ __launch_bounds__(256) void count_kernel(const int* __restrict__ dst,
                                                    const int* __restrict__ et,
                                                    int* __restrict__ cnt2, int E) {
    int e = blockIdx.x * 256 + threadIdx.x;
    if (e < E) atomicAdd(&cnt2[dst[e] * 8 + et[e]], 1);
}

// per-256-chunk sums
__global__ __launch_bounds__(256) void reduce_kernel(const int* __restrict__ cnt2,
                                                     int* __restrict__ bsum, int n) {
    __shared__ int ws[4];
    const int tid = threadIdx.x;
    int i = blockIdx.x * 256 + tid;
    int v = (i < n) ? cnt2[i] : 0;
#pragma unroll
    for (int off = 32; off > 0; off >>= 1) v += __shfl_down(v, off);
    if ((tid & 63) == 0) ws[tid >> 6] = v;
    __syncthreads();
    if (tid == 0) bsum[blockIdx.x] = ws[0] + ws[1] + ws[2] + ws[3];
}

// exclusive scan of cnt2 -> cur (each block sums its own bsum prefix); also inv2
__global__ __launch_bounds__(256) void apply_kernel(const int* __restrict__ cnt2,
                                                    const int* __restrict__ bsum,
                                                    int* __restrict__ cur,
                                                    float* __restrict__ inv2, int n) {
    __shared__ int wsum[4];
    __shared__ int bpre_s;
    const int tid = threadIdx.x;
    const int lane = tid & 63, wid = tid >> 6;
    int p = 0;
    for (int k = tid; k < blockIdx.x; k += 256) p += bsum[k];
#pragma unroll
    for (int off = 32; off > 0; off >>= 1) p += __shfl_down(p, off);
    if (lane == 0) wsum[wid] = p;
    __syncthreads();
    if (tid == 0) bpre_s = wsum[0] + wsum[1] + wsum[2] + wsum[3];
    __syncthreads();
    int i = blockIdx.x * 256 + tid;
    int x = (i < n) ? cnt2[i] : 0;
    int incl = x;
#pragma unroll
    for (int off = 1; off < 64; off <<= 1) {
        int t = __shfl_up(incl, off);
        if (lane >= off) incl += t;
    }
    __syncthreads();
    if (lane == 63) wsum[wid] = incl;
    __syncthreads();
    int wpre = 0;
    for (int k = 0; k < wid; ++k) wpre += wsum[k];
    if (i < n) {
        cur[i] = incl - x + wpre + bpre_s;
        inv2[i] = 1.0f / (float)max(x, 1);
    }
}

// counting-sort placement: epk sorted by (dst,rel), payload = src.
// post-condition: cur[b] == end offset of bucket b (start(b) = cur[b-1], cur[-1]=0)
__global__ __launch_bounds__(256) void place_kernel(const int* __restrict__ src,
                                                    const int* __restrict__ dst,
                                                    const int* __restrict__ et,
                                                    int* __restrict__ cur,
                                                    unsigned int* __restrict__ epk, int E) {
    int e = blockIdx.x * 256 + threadIdx.x;
    if (e < E) {
        int pos = atomicAdd(&cur[dst[e] * 8 + et[e]], 1);
        epk[pos] = (unsigned int)src[e];
    }
}

// ---------- merged dtype prep: blocks 0..17 transpose weights, rest convert x ----------
__global__ __launch_bounds__(256) void cvt_prep_kernel(const float* __restrict__ x,
                                                       unsigned short* __restrict__ xbf,
                                                       int n4,
                                                       const float* __restrict__ root1,
                                                       const float* __restrict__ W1,
                                                       const float* __restrict__ root2,
                                                       const float* __restrict__ W2,
                                                       unsigned short* __restrict__ Bt) {
    const int tid = threadIdx.x;
    if (blockIdx.x < 18) {
        // Bt[b][n*128+k] = bf16(W[k*128+n]), slab-transposed (16.5 KB LDS)
        __shared__ float S[32 * 129];
        const int b = blockIdx.x;
        const float* Ws;
        if (b == 0)       Ws = root1;
        else if (b < 9)   Ws = W1 + (size_t)(b - 1) * 16384;
        else if (b == 9)  Ws = root2;
        else              Ws = W2 + (size_t)(b - 10) * 16384;
        unsigned short* Bd = Bt + (size_t)b * 16384;
        for (int s = 0; s < 4; ++s) {
            __syncthreads();
#pragma unroll
            for (int i = 0; i < 16; ++i) {     // load rows k in [32s,32s+32)
                int idx = i * 256 + tid;
                int k = idx >> 7, n = idx & 127;
                S[k * 129 + n] = Ws[(size_t)(32 * s + k) * 128 + n];
            }
            __syncthreads();
#pragma unroll
            for (int i = 0; i < 16; ++i) {     // write Bd[n][32s+kk]
                int idx = i * 256 + tid;
                int n = idx >> 5, kk = idx & 31;
                Bd[n * 128 + 32 * s + kk] = f2bf(S[kk * 129 + n]);
            }
        }
    } else {
        // grid-stride fp32 -> bf16 of x
        const int stride = (gridDim.x - 18) * 256;
        for (int i = (blockIdx.x - 18) * 256 + tid; i < n4; i += stride) {
            float4 v = ((const float4*)x)[i];
            ushort4 o;
            o.x = f2bf(v.x); o.y = f2bf(v.y); o.z = f2bf(v.z); o.w = f2bf(v.w);
            ((ushort4*)xbf)[i] = o;
        }
    }
}

// ---------- input-space aggregation over (dst,rel)-sorted CSR (R7 version) ----------
// one wave per dst node; edge srcs prefetched lane-parallel, broadcast via shfl.
__global__ __launch_bounds__(256) void gather_agg(const unsigned short* __restrict__ xsrc,
                                                  const int* __restrict__ cur,
                                                  const unsigned int* __restrict__ epk,
                                                  const float* __restrict__ inv2,
                                                  unsigned short* __restrict__ agg, int N) {
    const int lane = threadIdx.x & 63;
    const int node = (int)((blockIdx.x * 256 + threadIdx.x) >> 6);
    if (node >= N) return;
    int b9 = 0;
    if (lane < 9) {
        int idx = node * 8 + lane - 1;
        b9 = (idx < 0) ? 0 : cur[idx];
    }
    float winv = (lane < 8) ? inv2[node * 8 + lane] : 0.f;
    const int beg0 = __builtin_amdgcn_readfirstlane(__shfl(b9, 0));
    const int end7 = __builtin_amdgcn_readfirstlane(__shfl(b9, 8));

    // lane-parallel prefetch of up to 64 edge srcs (covers virtually all nodes)
    unsigned int ep_v = 0;
    if (beg0 + lane < end7) ep_v = epk[beg0 + lane];

    const unsigned int* x32 = (const unsigned int*)xsrc;   // 2 bf16 per uint
    const size_t NH2 = (size_t)N * 64;
    unsigned int* agg32 = (unsigned int*)agg;

#pragma unroll
    for (int r = 0; r < 8; ++r) {
        const int beg = __builtin_amdgcn_readfirstlane(__shfl(b9, r));
        const int end = __builtin_amdgcn_readfirstlane(__shfl(b9, r + 1));
        float a0 = 0.f, a1 = 0.f;
        int e = beg;
        for (; e + 1 < end; e += 2) {     // 2 outstanding loads
            int i0 = e - beg0, i1 = i0 + 1;
            unsigned int s0 = (i0 < 64)
                ? (unsigned int)__builtin_amdgcn_readfirstlane(__shfl((int)ep_v, i0))
                : epk[e];
            unsigned int s1 = (i1 < 64)
                ? (unsigned int)__builtin_amdgcn_readfirstlane(__shfl((int)ep_v, i1))
                : epk[e + 1];
            unsigned int v0 = x32[(size_t)s0 * 64 + lane];
            unsigned int v1 = x32[(size_t)s1 * 64 + lane];
            a0 += __uint_as_float(v0 << 16);
            a1 += __uint_as_float(v0 & 0xffff0000u);
            a0 += __uint_as_float(v1 << 16);
            a1 += __uint_as_float(v1 & 0xffff0000u);
        }
        if (e < end) {
            int i0 = e - beg0;
            unsigned int s0 = (i0 < 64)
                ? (unsigned int)__builtin_amdgcn_readfirstlane(__shfl((int)ep_v, i0))
                : epk[e];
            unsigned int v0 = x32[(size_t)s0 * 64 + lane];
            a0 += __uint_as_float(v0 << 16);
            a1 += __uint_as_float(v0 & 0xffff0000u);
        }
        float w = __shfl(winv, r);
        unsigned int lo = f2bf(a0 * w);
        unsigned int hi = f2bf(a1 * w);
        agg32[(size_t)r * NH2 + (size_t)node * 64 + lane] = lo | (hi << 16);
    }
}

// ---------- fused layer GEMM: acc = A0@Bt[0] + sum_r agg[r]@Bt[1+r]  (K_eff = 1152) ----------
// R5/R7 structure: two-barrier VGPR staging per stage (no register prefetch — spills; see R6).
// mode 1: outb = bf16(relu(acc + bias))        mode 2: outf = relu(acc+bias).Wc + bc
__global__ __launch_bounds__(256, 2) void gemm_fused(const unsigned short* __restrict__ A0,
                                                     const unsigned short* __restrict__ agg,
                                                     const unsigned short* __restrict__ Bt9,
                                                     const float* __restrict__ bias,
                                                     const float* __restrict__ Wc,
                                                     const float* __restrict__ bc,
                                                     unsigned short* __restrict__ outb,
                                                     float* __restrict__ outf,
                                                     int M, int mode) {
    __shared__ __align__(16) unsigned short As[128 * LDA];
    __shared__ __align__(16) unsigned short Bs[128 * LDA];
    const int tid = threadIdx.x;
    const int rowBase = blockIdx.x * 128;
    const int wave = tid >> 6, lane = tid & 63;
    const int lm = lane & 15, lk = (lane >> 4) * 8;
    const size_t NH = (size_t)M * Hd;

    f32x4 acc[2][8];
#pragma unroll
    for (int mt = 0; mt < 2; ++mt)
#pragma unroll
        for (int nt = 0; nt < 8; ++nt) acc[mt][nt] = (f32x4){0.f, 0.f, 0.f, 0.f};

    for (int t = 0; t < 9; ++t) {
        const unsigned short* At = (t == 0) ? A0 : agg + (size_t)(t - 1) * NH;
        const unsigned short* Btt = Bt9 + (size_t)t * 16384;
        __syncthreads();   // previous stage's LDS reads complete
#pragma unroll
        for (int i = 0; i < 8; ++i) {
            int idx = i * 256 + tid;
            int r = idx >> 4, c16 = idx & 15;
            int grow = rowBase + r; if (grow >= M) grow = M - 1;
            *(float4*)&As[r * LDA + c16 * 8] = *(const float4*)&At[(size_t)grow * Hd + c16 * 8];
            *(float4*)&Bs[r * LDA + c16 * 8] = *(const float4*)&Btt[idx * 8];
        }
        __syncthreads();
#pragma unroll
        for (int ks = 0; ks < 4; ++ks) {
            const int k0 = ks * 32 + lk;
            short8 af0 = *(const short8*)&As[(wave * 32 + lm) * LDA + k0];
            short8 af1 = *(const short8*)&As[(wave * 32 + 16 + lm) * LDA + k0];
#pragma unroll
            for (int nt = 0; nt < 8; ++nt) {
                short8 bf = *(const short8*)&Bs[(nt * 16 + lm) * LDA + k0];
                acc[0][nt] = __builtin_amdgcn_mfma_f32_16x16x32_bf16(af0, bf, acc[0][nt], 0, 0, 0);
                acc[1][nt] = __builtin_amdgcn_mfma_f32_16x16x32_bf16(af1, bf, acc[1][nt], 0, 0, 0);
            }
        }
    }

    // epilogue. C/D layout: col = nt*16 + lm, row = wave*32 + mt*16 + (lane>>4)*4 + reg
    const int rquad = (lane >> 4) * 4;
    float biasr[8], wc[8];
#pragma unroll
    for (int nt = 0; nt < 8; ++nt) biasr[nt] = bias[nt * 16 + lm];
    if (mode == 2) {
#pragma unroll
        for (int nt = 0; nt < 8; ++nt) wc[nt] = Wc[nt * 16 + lm];
    }
    const float bc0 = (mode == 2) ? bc[0] : 0.f;

#pragma unroll
    for (int mt = 0; mt < 2; ++mt)
#pragma unroll
        for (int reg = 0; reg < 4; ++reg) {
            int row = rowBase + wave * 32 + mt * 16 + rquad + reg;
            if (mode == 1) {
                if (row >= M) continue;
#pragma unroll
                for (int nt = 0; nt < 8; ++nt) {
                    float v = fmaxf(acc[mt][nt][reg] + biasr[nt], 0.f);
                    outb[(size_t)row * Hd + nt * 16 + lm] = f2bf(v);
                }
            } else {
                float s = 0.f;
#pragma unroll
                for (int nt = 0; nt < 8; ++nt)
                    s += fmaxf(acc[mt][nt][reg] + biasr[nt], 0.f) * wc[nt];
                s += __shfl_xor(s, 1);
                s += __shfl_xor(s, 2);
                s += __shfl_xor(s, 4);
                s += __shfl_xor(s, 8);
                if (lm == 0 && row < M) outf[row] = s + bc0;
            }
        }
}

extern "C" void kernel_launch(void* const* d_in, const int* in_sizes, int n_in,
                              void* d_out, int out_size, void* d_ws, size_t ws_size,
                              hipStream_t stream) {
    const float* x     = (const float*)d_in[0];
    const int*   ei    = (const int*)d_in[1];
    const int*   et    = (const int*)d_in[2];
    const float* W1    = (const float*)d_in[3];
    const float* root1 = (const float*)d_in[4];
    const float* b1    = (const float*)d_in[5];
    const float* W2    = (const float*)d_in[6];
    const float* root2 = (const float*)d_in[7];
    const float* b2    = (const float*)d_in[8];
    const float* Wc    = (const float*)d_in[9];
    const float* bc    = (const float*)d_in[10];
    float* out = (float*)d_out;

    const int N = in_sizes[0] / Hd;
    const int E = in_sizes[2];
    const int R = in_sizes[3] / (Hd * Hd);   // == 8
    const int* src  = ei;
    const int* dstp = ei + E;

    const size_t NH = (size_t)N * Hd;
    const int n2 = N * 8;                    // (dst,rel) bucket count
    const int nBlocks2 = (n2 + 255) / 256;

    size_t off = 0;
    auto carve = [&](size_t bytes) -> char* {
        char* p = (char*)d_ws + off;
        off += (bytes + 255) & ~(size_t)255;
        return p;
    };
    unsigned short* xbf  = (unsigned short*)carve(NH * 2);
    unsigned short* hbf  = (unsigned short*)carve(NH * 2);
    unsigned short* agg  = (unsigned short*)carve((size_t)R * NH * 2);
    unsigned short* Bt   = (unsigned short*)carve((size_t)2 * 9 * 16384 * 2);
    int*            cnt2 = (int*)carve((size_t)n2 * 4);
    float*          inv2 = (float*)carve((size_t)n2 * 4);
    int*            cur  = (int*)carve((size_t)n2 * 4);
    int*            bsum = (int*)carve((size_t)nBlocks2 * 4);
    unsigned int*   epk  = (unsigned int*)carve((size_t)E * 4);
    if (off > ws_size) return;

    // graph prep: histogram -> inv + CSR over (dst*8+rel)
    hipMemsetAsync(cnt2, 0, (size_t)n2 * 4, stream);
    count_kernel<<<(E + 255) / 256, 256, 0, stream>>>(dstp, et, cnt2, E);
    reduce_kernel<<<nBlocks2, 256, 0, stream>>>(cnt2, bsum, n2);
    apply_kernel<<<nBlocks2, 256, 0, stream>>>(cnt2, bsum, cur, inv2, n2);
    place_kernel<<<(E + 255) / 256, 256, 0, stream>>>(src, dstp, et, cur, epk, E);

    // dtype prep: weights transpose (blocks 0..17) + x cvt (grid-stride)
    const int n4 = (int)(NH / 4);
    cvt_prep_kernel<<<18 + 512, 256, 0, stream>>>(x, xbf, n4, root1, W1, root2, W2, Bt);

    const int Mtiles = (N + 127) / 128;
    const int nodeBlocks = (N + 3) / 4;

    // layer 1: aggregate x -> agg; fused GEMM -> hbf (relu, bf16)
    gather_agg<<<nodeBlocks, 256, 0, stream>>>(xbf, cur, epk, inv2, agg, N);
    gemm_fused<<<Mtiles, 256, 0, stream>>>(xbf, agg, Bt, b1, nullptr, nullptr,
                                           hbf, nullptr, N, 1);
    // layer 2: aggregate hbf -> agg; fused GEMM + classifier -> out
    gather_agg<<<nodeBlocks, 256, 0, stream>>>(hbf, cur, epk, inv2, agg, N);
    gemm_fused<<<Mtiles, 256, 0, stream>>>(hbf, agg, Bt + (size_t)9 * 16384, b2, Wc, bc,
                                           nullptr, out, N, 2);
}